// Round 17
// baseline (256.673 us; speedup 1.0000x reference)
//
#include <hip/hip_runtime.h>
#include <hip/hip_bf16.h>
#include <cstdint>

#define B_SZ   4096
#define F_SZ   30
#define D_SZ   128
#define P_SZ   435
#define BM     128
#define PCH    15                     // consecutive pairs per block
#define NCHUNK 29                     // 435 / 15
#define FD     (F_SZ * D_SZ)          // 3840
#define W_ELEMS    (P_SZ * D_SZ * D_SZ)
#define GRID_MAIN  (NCHUNK * 32)      // 928 = 8 * 116

typedef __bf16 bf16x8 __attribute__((ext_vector_type(8)));
typedef float  f32x4  __attribute__((ext_vector_type(4)));
typedef unsigned short u16x8 __attribute__((ext_vector_type(8)));
typedef unsigned short u16x4 __attribute__((ext_vector_type(4)));

__device__ __forceinline__ unsigned short f2bf(float x) {
    unsigned int u = __float_as_uint(x);
    u += 0x7fffu + ((u >> 16) & 1u);
    return (unsigned short)(u >> 16);
}
__device__ __forceinline__ void gl_lds16(const void* g, void* l) {
    __builtin_amdgcn_global_load_lds(
        (const __attribute__((address_space(1))) unsigned int*)g,
        (__attribute__((address_space(3))) unsigned int*)l, 16, 0, 0);
}
#define LGKM_BAR() do { \
    asm volatile("s_waitcnt lgkmcnt(0)" ::: "memory"); \
    __builtin_amdgcn_s_barrier(); } while (0)
#define WAVE_FENCE() asm volatile("s_waitcnt lgkmcnt(0)" ::: "memory")

// convert 8 consecutive floats -> bf16x8 fragment
__device__ __forceinline__ bf16x8 ld_frag_f32(const float* src) {
    f32x4 a = *reinterpret_cast<const f32x4*>(src);
    f32x4 b = *reinterpret_cast<const f32x4*>(src + 4);
    u16x8 v;
    v[0]=f2bf(a[0]); v[1]=f2bf(a[1]); v[2]=f2bf(a[2]); v[3]=f2bf(a[3]);
    v[4]=f2bf(b[0]); v[5]=f2bf(b[1]); v[6]=f2bf(b[2]); v[7]=f2bf(b[3]);
    return *reinterpret_cast<bf16x8*>(&v);
}

__global__ __launch_bounds__(256)
void cvt_bf16_kernel(const float* __restrict__ src,
                     unsigned short* __restrict__ dst, int n8) {
    int stride = gridDim.x * blockDim.x;
    for (int i = blockIdx.x * blockDim.x + threadIdx.x; i < n8; i += stride) {
        const float* s = src + (size_t)i * 8;
        f32x4 a = *reinterpret_cast<const f32x4*>(s);
        f32x4 b = *reinterpret_cast<const f32x4*>(s + 4);
        u16x8 v;
        v[0]=f2bf(a[0]); v[1]=f2bf(a[1]); v[2]=f2bf(a[2]); v[3]=f2bf(a[3]);
        v[4]=f2bf(b[0]); v[5]=f2bf(b[1]); v[6]=f2bf(b[2]); v[7]=f2bf(b[3]);
        *reinterpret_cast<u16x8*>(dst + (size_t)i * 8) = v;
    }
}

// block = (b-tile 128 rows, 15 consecutive pairs), 512 thr / 8 waves.
// vj and A-fragments read DIRECTLY from fp32 femb (no femb bf16 pass);
// W pre-converted to bf16 in d_ws. Same-chunk blocks dispatch-adjacent per
// XCD for W L2 reuse. Wave-private epilogue transpose in dead Ws[cur].
__global__ __launch_bounds__(512, 2)
void bilinear_kernel(const float* __restrict__ femb,
                     const unsigned short* __restrict__ wsW,
                     float* __restrict__ out) {
    __shared__ unsigned short Ws[2][D_SZ * D_SZ];   // 2 x 32 KB

    const int orig  = blockIdx.x;
    const int btgrp = orig & 7;
    const int idx   = orig >> 3;          // 0..115
    const int btsub = idx & 3;            // same-chunk blocks adjacent
    const int chunk = idx >> 2;           // 0..28
    const int m0    = (btgrp * 4 + btsub) * BM;
    const int p0    = chunk * PCH;

    int fi = 0, rem = p0;
    while (rem >= F_SZ - 1 - fi) { rem -= F_SZ - 1 - fi; ++fi; }
    int fj = fi + 1 + rem;

    const int tid  = threadIdx.x;
    const int lane = tid & 63;
    const int wave = tid >> 6;      // 0..7
    const int l16  = lane >> 4;
    const int lc   = lane & 15;
    const int wrow = wave * 16;     // this wave's b-sub-tile base

    const int rb_rl = lane >> 5;          // +2 per iter
    const int rb_c  = lane & 31;

    bf16x8 afr[4];

    // ---- prologue: gl_lds W(p0) -> Ws[0]; afr(fi) from fp32 femb ----
    {
        const unsigned short* baseW = wsW + (size_t)p0 * (D_SZ * D_SZ);
        #pragma unroll
        for (int it = 0; it < 4; ++it) {
            int r0 = it * 32 + wave * 4;
            int rl = r0 + l16;
            int cs = lc ^ (rl & 7);
            gl_lds16(baseW + rl * 128 + cs * 8, &Ws[0][r0 * 128]);
        }
        const float* ar = femb + (size_t)(m0 + wrow + lc) * FD + fi * D_SZ;
        #pragma unroll
        for (int kk = 0; kk < 4; ++kk)
            afr[kk] = ld_frag_f32(ar + (kk * 4 + l16) * 8);
    }
    __syncthreads();    // full drain once (gl_lds prologue)

    int s = 0;

#define STEP(CUR) do {                                                        \
    const int p = p0 + s;                                                     \
    const bool has_next = (s + 1 < PCH);                                      \
    int fi_n = fi, fj_n = fj; bool achg = false;                              \
    if (has_next) {                                                           \
        const bool wrap = (fj == F_SZ - 1);                                   \
        fi_n = wrap ? fi + 1 : fi;                                            \
        fj_n = wrap ? fi + 2 : fj + 1;                                        \
        achg = wrap;                                                          \
        const unsigned short* baseW = wsW + (size_t)(p + 1) * (D_SZ * D_SZ);  \
        _Pragma("unroll")                                                     \
        for (int it = 0; it < 4; ++it) {                                      \
            int r0 = it * 32 + wave * 4;                                      \
            int rl = r0 + l16;                                                \
            int cs = lc ^ (rl & 7);                                           \
            gl_lds16(baseW + rl * 128 + cs * 8, &Ws[CUR ^ 1][r0 * 128]);      \
        }                                                                     \
    }                                                                         \
    /* vj for CURRENT step: fp32 direct, 16B contiguous per lane */           \
    f32x4 vjreg[8];                                                           \
    _Pragma("unroll")                                                         \
    for (int h = 0; h < 2; ++h)                                               \
        _Pragma("unroll")                                                     \
        for (int i = 0; i < 4; ++i) {                                         \
            int b = m0 + wrow + h * 8 + i * 2 + rb_rl;                        \
            vjreg[h * 4 + i] = *reinterpret_cast<const f32x4*>(               \
                femb + (size_t)b * FD + fj * D_SZ + rb_c * 4);                \
        }                                                                     \
    f32x4 acc[8];                                                             \
    _Pragma("unroll")                                                         \
    for (int n = 0; n < 8; ++n) acc[n] = (f32x4)0.0f;                         \
    _Pragma("unroll")                                                         \
    for (int n = 0; n < 8; ++n) {                                             \
        int el = n * 16 + lc;                                                 \
        _Pragma("unroll")                                                     \
        for (int kk = 0; kk < 4; ++kk) {                                      \
            bf16x8 wfr = *reinterpret_cast<const bf16x8*>(                    \
                &Ws[CUR][el * 128 + (((kk * 4 + l16) ^ (el & 7)) * 8)]);      \
            acc[n] = __builtin_amdgcn_mfma_f32_16x16x32_bf16(                 \
                wfr, afr[kk], acc[n], 0, 0, 0);                               \
        }                                                                     \
    }                                                                         \
    LGKM_BAR();   /* all waves done reading Ws[CUR]; it becomes scratch */    \
    {                                                                         \
        float* swav = reinterpret_cast<float*>(&Ws[CUR][0]) + wave * 1024;    \
        _Pragma("unroll")                                                     \
        for (int h = 0; h < 2; ++h) {                                         \
            if ((lc >> 3) == h) {                                             \
                int rl = lc & 7;                                              \
                _Pragma("unroll")                                             \
                for (int n = 0; n < 8; ++n) {                                 \
                    int c = n * 4 + l16;                                      \
                    *reinterpret_cast<f32x4*>(                                \
                        &swav[(rl * 32 + (c ^ rl)) * 4]) = acc[n];            \
                }                                                             \
            }                                                                 \
            WAVE_FENCE();   /* dump visible before cross-lane readback */     \
            _Pragma("unroll")                                                 \
            for (int i = 0; i < 4; ++i) {                                     \
                int rl = i * 2 + rb_rl;                                       \
                f32x4 v = *reinterpret_cast<const f32x4*>(                    \
                    &swav[(rl * 32 + (rb_c ^ rl)) * 4]);                      \
                int b = m0 + wrow + h * 8 + rl;                               \
                f32x4 vjb = vjreg[h * 4 + i];                                 \
                f32x4 o;                                                      \
                o[0] = v[0] * vjb[0];                                         \
                o[1] = v[1] * vjb[1];                                         \
                o[2] = v[2] * vjb[2];                                         \
                o[3] = v[3] * vjb[3];                                         \
                __builtin_nontemporal_store(o, reinterpret_cast<f32x4*>(      \
                    out + ((size_t)b * P_SZ + p) * D_SZ + rb_c * 4));         \
            }                                                                 \
            WAVE_FENCE();   /* readback done before next-h dump overwrites */ \
        }                                                                     \
    }                                                                         \
    if (has_next) {                                                           \
        if (achg) {                                                           \
            const float* ar =                                                 \
                femb + (size_t)(m0 + wrow + lc) * FD + fi_n * D_SZ;           \
            _Pragma("unroll")                                                 \
            for (int kk = 0; kk < 4; ++kk)                                    \
                afr[kk] = ld_frag_f32(ar + (kk * 4 + l16) * 8);               \
        }                                                                     \
        asm volatile("s_waitcnt vmcnt(8) lgkmcnt(0)" ::: "memory");           \
        __builtin_amdgcn_s_barrier();                                         \
    }                                                                         \
    fi = fi_n; fj = fj_n;                                                     \
} while (0)

    while (true) {
        STEP(0);
        if (++s >= PCH) break;
        STEP(1);
        if (++s >= PCH) break;
    }
#undef STEP
}

extern "C" void kernel_launch(void* const* d_in, const int* in_sizes, int n_in,
                              void* d_out, int out_size, void* d_ws, size_t ws_size,
                              hipStream_t stream) {
    const float* femb = (const float*)d_in[0];
    const float* W    = (const float*)d_in[1];
    float* out        = (float*)d_out;

    unsigned short* wsW = (unsigned short*)d_ws;

    hipLaunchKernelGGL(cvt_bf16_kernel, dim3(2048), dim3(256), 0, stream,
                       W, wsW, W_ELEMS / 8);
    hipLaunchKernelGGL(bilinear_kernel, dim3(GRID_MAIN), dim3(512), 0, stream,
                       femb, wsW, out);
}

// Round 18
// 211.675 us; speedup vs baseline: 1.2126x; 1.2126x over previous
//
#include <hip/hip_runtime.h>
#include <hip/hip_bf16.h>
#include <cstdint>

#define B_SZ   4096
#define F_SZ   30
#define D_SZ   128
#define P_SZ   435
#define PCH    15                     // consecutive pairs per block
#define NCHUNK 29                     // 435 / 15
#define FD     (F_SZ * D_SZ)          // 3840
#define FEMB_ELEMS (B_SZ * F_SZ * D_SZ)
#define W_ELEMS    (P_SZ * D_SZ * D_SZ)
#define GRID_MAIN  (NCHUNK * 2 * 8)   // 464 = 8 XCD x 58; all resident

typedef __bf16 bf16x8 __attribute__((ext_vector_type(8)));
typedef float  f32x4  __attribute__((ext_vector_type(4)));
typedef unsigned short u16x8 __attribute__((ext_vector_type(8)));
typedef unsigned short u16x4 __attribute__((ext_vector_type(4)));

__device__ __forceinline__ unsigned short f2bf(float x) {
    unsigned int u = __float_as_uint(x);
    u += 0x7fffu + ((u >> 16) & 1u);
    return (unsigned short)(u >> 16);
}
__device__ __forceinline__ float bf2f(unsigned short v) {
    return __uint_as_float(((unsigned int)v) << 16);
}
__device__ __forceinline__ void gl_lds16(const void* g, void* l) {
    __builtin_amdgcn_global_load_lds(
        (const __attribute__((address_space(1))) unsigned int*)g,
        (__attribute__((address_space(3))) unsigned int*)l, 16, 0, 0);
}
#define LGKM_BAR() do { \
    asm volatile("s_waitcnt lgkmcnt(0)" ::: "memory"); \
    __builtin_amdgcn_s_barrier(); } while (0)
#define WAVE_FENCE() asm volatile("s_waitcnt lgkmcnt(0)" ::: "memory")

__global__ __launch_bounds__(256)
void cvt_bf16_kernel(const float* __restrict__ src,
                     unsigned short* __restrict__ dst, int n8) {
    int stride = gridDim.x * blockDim.x;
    for (int i = blockIdx.x * blockDim.x + threadIdx.x; i < n8; i += stride) {
        const float* s = src + (size_t)i * 8;
        f32x4 a = *reinterpret_cast<const f32x4*>(s);
        f32x4 b = *reinterpret_cast<const f32x4*>(s + 4);
        u16x8 v;
        v[0]=f2bf(a[0]); v[1]=f2bf(a[1]); v[2]=f2bf(a[2]); v[3]=f2bf(a[3]);
        v[4]=f2bf(b[0]); v[5]=f2bf(b[1]); v[6]=f2bf(b[2]); v[7]=f2bf(b[3]);
        *reinterpret_cast<u16x8*>(dst + (size_t)i * 8) = v;
    }
}

// block = (256 b-rows = 2 btiles, 15 consecutive pairs), 512 thr / 8 waves.
// 464 blocks: all resident (no dispatch tail). One W stage feeds both btiles
// (W L2 traffic halved; each wfr LDS read feeds 2 MFMAs). Wave-private
// epilogue transpose in dead Ws[cur], 4 rounds (btile x half). All loads of
// a step issue before its NT stores; end-of-step vmcnt(16) keeps stores in
// flight.
__global__ __launch_bounds__(512, 2)
void bilinear_kernel(const unsigned short* __restrict__ wsA,
                     const unsigned short* __restrict__ wsW,
                     float* __restrict__ out) {
    __shared__ unsigned short Ws[2][D_SZ * D_SZ];   // 2 x 32 KB

    const int orig  = blockIdx.x;
    const int btgrp = orig & 7;           // XCD
    const int idx   = orig >> 3;          // 0..57
    const int btsub = idx & 1;            // same-chunk blocks adjacent
    const int chunk = idx >> 1;           // 0..28
    const int m0    = btgrp * 512 + btsub * 256;
    const int p0    = chunk * PCH;

    int fi = 0, rem = p0;
    while (rem >= F_SZ - 1 - fi) { rem -= F_SZ - 1 - fi; ++fi; }
    int fj = fi + 1 + rem;

    const int tid  = threadIdx.x;
    const int lane = tid & 63;
    const int wave = tid >> 6;      // 0..7
    const int l16  = lane >> 4;
    const int lc   = lane & 15;
    const int wrow = wave * 16;     // wave's row base within each btile

    const int rb_rl = lane >> 5;          // +2 per readback iter
    const int rb_c  = lane & 31;

    bf16x8 afr0[4], afr1[4];

    // ---- prologue: gl_lds W(p0) -> Ws[0]; afr for both btiles ----
    {
        const unsigned short* baseW = wsW + (size_t)p0 * (D_SZ * D_SZ);
        #pragma unroll
        for (int it = 0; it < 4; ++it) {
            int r0 = it * 32 + wave * 4;
            int rl = r0 + l16;
            int cs = lc ^ (rl & 7);
            gl_lds16(baseW + rl * 128 + cs * 8, &Ws[0][r0 * 128]);
        }
        const unsigned short* ar0 =
            wsA + (size_t)(m0 + wrow + lc) * FD + fi * D_SZ;
        #pragma unroll
        for (int kk = 0; kk < 4; ++kk) {
            afr0[kk] = *reinterpret_cast<const bf16x8*>(ar0 + (kk * 4 + l16) * 8);
            afr1[kk] = *reinterpret_cast<const bf16x8*>(
                ar0 + (size_t)128 * FD + (kk * 4 + l16) * 8);
        }
    }
    __syncthreads();    // full drain once (gl_lds prologue)

    int s = 0;

#define EPI(ACC, BT) do {                                                     \
    _Pragma("unroll")                                                         \
    for (int h = 0; h < 2; ++h) {                                             \
        if ((lc >> 3) == h) {                                                 \
            int rl = lc & 7;                                                  \
            _Pragma("unroll")                                                 \
            for (int n = 0; n < 8; ++n) {                                     \
                int c = n * 4 + l16;                                          \
                *reinterpret_cast<f32x4*>(                                    \
                    &swav[(rl * 32 + (c ^ rl)) * 4]) = ACC[n];                \
            }                                                                 \
        }                                                                     \
        WAVE_FENCE();   /* dump visible before cross-lane readback */         \
        _Pragma("unroll")                                                     \
        for (int i = 0; i < 4; ++i) {                                         \
            int rl = i * 2 + rb_rl;                                           \
            f32x4 v = *reinterpret_cast<const f32x4*>(                        \
                &swav[(rl * 32 + (rb_c ^ rl)) * 4]);                          \
            int b = m0 + (BT) * 128 + wrow + h * 8 + rl;                      \
            u16x4 vjb = vjreg[(BT) * 8 + h * 4 + i];                          \
            f32x4 o;                                                          \
            o[0] = v[0] * bf2f(vjb[0]);                                       \
            o[1] = v[1] * bf2f(vjb[1]);                                       \
            o[2] = v[2] * bf2f(vjb[2]);                                       \
            o[3] = v[3] * bf2f(vjb[3]);                                       \
            __builtin_nontemporal_store(o, reinterpret_cast<f32x4*>(          \
                out + ((size_t)b * P_SZ + p) * D_SZ + rb_c * 4));             \
        }                                                                     \
        WAVE_FENCE();   /* readback done before next dump overwrites */       \
    }                                                                         \
} while (0)

#define STEP(CUR) do {                                                        \
    const int p = p0 + s;                                                     \
    const bool has_next = (s + 1 < PCH);                                      \
    int fi_n = fi, fj_n = fj; bool achg = false;                              \
    if (has_next) {                                                           \
        const bool wrap = (fj == F_SZ - 1);                                   \
        fi_n = wrap ? fi + 1 : fi;                                            \
        fj_n = wrap ? fi + 2 : fj + 1;                                        \
        achg = wrap;                                                          \
        const unsigned short* baseW = wsW + (size_t)(p + 1) * (D_SZ * D_SZ);  \
        _Pragma("unroll")                                                     \
        for (int it = 0; it < 4; ++it) {                                      \
            int r0 = it * 32 + wave * 4;                                      \
            int rl = r0 + l16;                                                \
            int cs = lc ^ (rl & 7);                                           \
            gl_lds16(baseW + rl * 128 + cs * 8, &Ws[CUR ^ 1][r0 * 128]);      \
        }                                                                     \
    }                                                                         \
    /* vj for both btiles, bf16, 8B contiguous per lane */                    \
    u16x4 vjreg[16];                                                          \
    _Pragma("unroll")                                                         \
    for (int bt = 0; bt < 2; ++bt)                                            \
        _Pragma("unroll")                                                     \
        for (int h = 0; h < 2; ++h)                                           \
            _Pragma("unroll")                                                 \
            for (int i = 0; i < 4; ++i) {                                     \
                int b = m0 + bt * 128 + wrow + h * 8 + i * 2 + rb_rl;         \
                vjreg[bt * 8 + h * 4 + i] = *reinterpret_cast<const u16x4*>(  \
                    wsA + (size_t)b * FD + fj * D_SZ + rb_c * 4);             \
            }                                                                 \
    f32x4 acc0[8], acc1[8];                                                   \
    _Pragma("unroll")                                                         \
    for (int n = 0; n < 8; ++n) { acc0[n] = (f32x4)0.0f; acc1[n] = (f32x4)0.0f; } \
    _Pragma("unroll")                                                         \
    for (int n = 0; n < 8; ++n) {                                             \
        int el = n * 16 + lc;                                                 \
        _Pragma("unroll")                                                     \
        for (int kk = 0; kk < 4; ++kk) {                                      \
            bf16x8 wfr = *reinterpret_cast<const bf16x8*>(                    \
                &Ws[CUR][el * 128 + (((kk * 4 + l16) ^ (el & 7)) * 8)]);      \
            acc0[n] = __builtin_amdgcn_mfma_f32_16x16x32_bf16(                \
                wfr, afr0[kk], acc0[n], 0, 0, 0);                             \
            acc1[n] = __builtin_amdgcn_mfma_f32_16x16x32_bf16(                \
                wfr, afr1[kk], acc1[n], 0, 0, 0);                             \
        }                                                                     \
    }                                                                         \
    /* A reload BEFORE stores so end-of-step vmcnt leaves only stores */      \
    if (has_next && achg) {                                                   \
        const unsigned short* ar0 =                                           \
            wsA + (size_t)(m0 + wrow + lc) * FD + fi_n * D_SZ;                \
        _Pragma("unroll")                                                     \
        for (int kk = 0; kk < 4; ++kk) {                                      \
            afr0[kk] = *reinterpret_cast<const bf16x8*>(                      \
                ar0 + (kk * 4 + l16) * 8);                                    \
            afr1[kk] = *reinterpret_cast<const bf16x8*>(                      \
                ar0 + (size_t)128 * FD + (kk * 4 + l16) * 8);                 \
        }                                                                     \
    }                                                                         \
    LGKM_BAR();   /* all waves done reading Ws[CUR]; it becomes scratch */    \
    {                                                                         \
        float* swav = reinterpret_cast<float*>(&Ws[CUR][0]) + wave * 1024;    \
        EPI(acc0, 0);                                                         \
        EPI(acc1, 1);                                                         \
    }                                                                         \
    if (has_next) {                                                           \
        /* retire all loads (oldest), keep the 16 NT stores in flight */      \
        asm volatile("s_waitcnt vmcnt(16) lgkmcnt(0)" ::: "memory");          \
        __builtin_amdgcn_s_barrier();                                         \
    }                                                                         \
    fi = fi_n; fj = fj_n;                                                     \
} while (0)

    while (true) {
        STEP(0);
        if (++s >= PCH) break;
        STEP(1);
        if (++s >= PCH) break;
    }
#undef STEP
#undef EPI
}

extern "C" void kernel_launch(void* const* d_in, const int* in_sizes, int n_in,
                              void* d_out, int out_size, void* d_ws, size_t ws_size,
                              hipStream_t stream) {
    const float* femb = (const float*)d_in[0];
    const float* W    = (const float*)d_in[1];
    float* out        = (float*)d_out;

    unsigned short* wsA = (unsigned short*)d_ws;
    unsigned short* wsW = wsA + FEMB_ELEMS;

    hipLaunchKernelGGL(cvt_bf16_kernel, dim3(2048), dim3(256), 0, stream,
                       femb, wsA, FEMB_ELEMS / 8);
    hipLaunchKernelGGL(cvt_bf16_kernel, dim3(2048), dim3(256), 0, stream,
                       W, wsW, W_ELEMS / 8);
    hipLaunchKernelGGL(bilinear_kernel, dim3(GRID_MAIN), dim3(512), 0, stream,
                       wsA, wsW, out);
}